// Round 16
// baseline (90.321 us; speedup 1.0000x reference)
//
#include <hip/hip_runtime.h>
#include <math.h>

// ---------------------------------------------------------------------------
// QMixer forward, round 16: r15 + software-pipelined hyper chunk loop.
// r15 accounting: attn ~29us (73% of HBM-share floor), hyper ~38us (2.2x its
// floor, latency-bound). Remaining WAR hazard (r7 class): chunk loop's
// h1 -> tile -> w1 serialization. Pipeline with ONE tile: per iter, read w1
// A-frags of chunk mc-1 early, run chunk mc's h1 MFMAs (independent), w1 +
// epilogue of mc-1, then write tile = h1(mc). Program-order LDS
// read-before-write on the wave-private tile keeps it safe (in-order DS).
// attn/setup byte-identical to r15.
// ---------------------------------------------------------------------------

#define TOKS 32768

typedef __attribute__((ext_vector_type(8))) short short8;
typedef __attribute__((ext_vector_type(4))) float f32x4;

#define MFMA(a, b, c) __builtin_amdgcn_mfma_f32_16x16x32_bf16((a), (b), (c), 0, 0, 0)

// ws element offsets (ushort units for bf16 part) -- all regions SWIZZLED
#define E_CAT   0          // [64][128]
#define E_WQKT  8192       // [80][64]  (row 64 = u)
#define E_ZBRT  13312      // [128][128]
#define E_H1T   29696      // [64][192]
#define E_W2T   41984      // [32][64]
#define E_WFT   44032      // [32][64]
#define E_BF16_TOTAL 46080 // floats (192) start at byte 92160
#define E_AO_US 46464      // ao[32768][64] bf16

__device__ __forceinline__ unsigned short bfr(float x) {
    unsigned u = __builtin_bit_cast(unsigned, x);
    u += 0x7fffu + ((u >> 16) & 1u);           // round-to-nearest-even
    return (unsigned short)(u >> 16);
}
__device__ __forceinline__ float bf2f(unsigned short h) {
    unsigned u = ((unsigned)h) << 16;
    return __builtin_bit_cast(float, u);
}
__device__ __forceinline__ short8 cvt8v(float4 a, float4 b) {
    short8 r;
    r[0] = (short)bfr(a.x); r[1] = (short)bfr(a.y);
    r[2] = (short)bfr(a.z); r[3] = (short)bfr(a.w);
    r[4] = (short)bfr(b.x); r[5] = (short)bfr(b.y);
    r[6] = (short)bfr(b.z); r[7] = (short)bfr(b.w);
    return r;
}
#define SWZ64(r, c)  ((((r) * 64)  + (c)) ^ (((r) & 7) << 3))
#define SWZ128(r, c) ((((r) * 128) + (c)) ^ (((r) & 7) << 3))
#define SWZ192(r, c) ((((r) * 192) + (c)) ^ (((r) & 7) << 3))

// ---------------------------------------------------------------------------
__global__ __launch_bounds__(256) void qmix_setup(
    const float* __restrict__ ally_w, const float* __restrict__ enemy_w,
    const float* __restrict__ q_w, const float* __restrict__ k_w,
    const float* __restrict__ k_b,
    const float* __restrict__ hw1_w1, const float* __restrict__ hw1_b1,
    const float* __restrict__ hw1_w2,
    const float* __restrict__ hwf_w1, const float* __restrict__ hwf_b1,
    const float* __restrict__ hwf_w2,
    const float* __restrict__ hb1_w, const float* __restrict__ hb1_b,
    const float* __restrict__ v_w1, const float* __restrict__ v_b1,
    const float* __restrict__ tre_w, const float* __restrict__ tre_b,
    unsigned short* __restrict__ wsb, float* __restrict__ wsf)
{
    int gid = blockIdx.x * 256 + threadIdx.x;
    if (gid < E_BF16_TOTAL) {
        float v = 0.f;
        int base, r, c, K;
        if (gid < E_WQKT) {                         // CAT [64][128]
            base = E_CAT; K = 128;
            int i = gid - base; r = i >> 7; c = i & 127;
            v = (c < 64) ? ally_w[c * 64 + r] : enemy_w[(c - 64) * 64 + r];
        } else if (gid < E_ZBRT) {                  // WQKT [80][64]
            base = E_WQKT; K = 64;
            int i = gid - base; r = i >> 6; c = i & 63;
            if (r < 64) {
                for (int g = 0; g < 64; ++g) v += q_w[c * 64 + g] * k_w[r * 64 + g];
            } else if (r == 64) {
                for (int g = 0; g < 64; ++g) v += q_w[c * 64 + g] * k_b[g];
            }
        } else if (gid < E_H1T) {                   // ZBRT [128][128]
            base = E_ZBRT; K = 128;
            int i = gid - base; r = i >> 7; c = i & 127;
            if (r < 64) {
                if (c < 64) v = hwf_w1[c * 64 + r];
                else for (int g = 0; g < 64; ++g) v += tre_w[(c - 64) * 64 + g] * hwf_w1[(64 + g) * 64 + r];
            } else if (r < 96) {
                int m = r - 64;
                if (c < 64) v = hb1_w[c * 32 + m];
                else for (int g = 0; g < 64; ++g) v += tre_w[(c - 64) * 64 + g] * hb1_w[(64 + g) * 32 + m];
            } else {
                int m = r - 96;
                if (c < 64) v = v_w1[c * 32 + m];
                else for (int g = 0; g < 64; ++g) v += tre_w[(c - 64) * 64 + g] * v_w1[(64 + g) * 32 + m];
            }
        } else if (gid < E_W2T) {                   // H1T [64][192]
            base = E_H1T; K = 192;
            int i = gid - base; r = i / 192; c = i % 192;
            if (c < 64) v = hw1_w1[(64 + c) * 64 + r];
            else if (c < 128) {
                for (int g = 0; g < 64; ++g) v += tre_w[(c - 64) * 64 + g] * hw1_w1[(128 + g) * 64 + r];
            } else v = hw1_w1[(c - 128) * 64 + r];
        } else if (gid < E_WFT) {                   // W2T [32][64]
            base = E_W2T; K = 64;
            int i = gid - base; r = i >> 6; c = i & 63;
            v = hw1_w2[c * 32 + r];
        } else {                                    // WFT [32][64]
            base = E_WFT; K = 64;
            int i = gid - base; r = i >> 6; c = i & 63;
            v = hwf_w2[c * 32 + r];
        }
        wsb[base + ((r * K + c) ^ ((r & 7) << 3))] = bfr(v);
    } else if (gid < E_BF16_TOTAL + 192) {
        int j = gid - E_BF16_TOTAL; float v;
        if (j < 64) {
            v = hw1_b1[j];
            for (int g = 0; g < 64; ++g) v += tre_b[g] * hw1_w1[(128 + g) * 64 + j];
        } else if (j < 128) {
            int e = j - 64; v = hwf_b1[e];
            for (int g = 0; g < 64; ++g) v += tre_b[g] * hwf_w1[(64 + g) * 64 + e];
        } else if (j < 160) {
            int m = j - 128; v = hb1_b[m];
            for (int g = 0; g < 64; ++g) v += tre_b[g] * hb1_w[(64 + g) * 32 + m];
        } else {
            int m = j - 160; v = v_b1[m];
            for (int g = 0; g < 64; ++g) v += tre_b[g] * v_w1[(64 + g) * 32 + m];
        }
        wsf[j] = v;
    }
}

// ---------------------------------------------------------------------------
// Kernel A: attention (r15 body). 512 threads, ONE token per wave.
__global__ __launch_bounds__(512) void qmix_attn(
    const float* __restrict__ states,
    const float* __restrict__ ally_b, const float* __restrict__ enemy_b,
    const unsigned short* __restrict__ wsb,
    unsigned short* __restrict__ aoG)
{
    __shared__ unsigned short sWa[13312];      // CAT 8192 + WQKT 5120 (26KB)
    __shared__ unsigned short sE[8][1024];
    __shared__ unsigned short sT[8][1024];     // tmp tile; PW overlay after D

    const int lane = threadIdx.x & 63;
    const int wv   = threadIdx.x >> 6;
    const int l15  = lane & 15;
    const int lg   = lane >> 4;
    const int kb   = lg * 8;
    const size_t t = (size_t)blockIdx.x * 8 + wv;

    const short8 zero8 = {0, 0, 0, 0, 0, 0, 0, 0};
    const f32x4  zero4 = {0.f, 0.f, 0.f, 0.f};

    for (int i = threadIdx.x * 8; i < 13312; i += 512 * 8)
        *(short8*)(sWa + i) = *(const short8*)(wsb + E_CAT + i);

    const int roff = (l15 < 8) ? (l15 * 64 + kb) : (512 + (l15 - 8) * 64 + kb);
    const float* p = states + t * 1024 + roff;
    float4 cur0 = *(const float4*)(p);
    float4 cur1 = *(const float4*)(p + 4);
    float4 cur2 = *(const float4*)(p + 32);
    float4 cur3 = *(const float4*)(p + 36);

    float biasEnt[4];
    #pragma unroll
    for (int nt = 0; nt < 4; ++nt) {
        int col = nt * 16 + l15;
        biasEnt[nt] = (lg < 2) ? ally_b[col] : enemy_b[col];
    }
    __syncthreads();
    const unsigned short* lCAT  = sWa;
    const unsigned short* lWQKT = sWa + 8192;

    unsigned short* E = sE[wv];
    unsigned short* T = sT[wv];

    short8 a01 = cvt8v(cur0, cur1);
    short8 a23 = cvt8v(cur2, cur3);
    const bool isally = (l15 < 8);

    // ---- B: ent = [ally;enemy] @ CAT (block-diag K=128) ----
    f32x4 accB[4] = {zero4, zero4, zero4, zero4};
    #pragma unroll
    for (int ks = 0; ks < 4; ++ks) {
        short8 af;
        if (ks == 0)      af = isally ? a01 : zero8;
        else if (ks == 1) af = isally ? a23 : zero8;
        else if (ks == 2) af = isally ? zero8 : a01;
        else              af = isally ? zero8 : a23;
        #pragma unroll
        for (int nt = 0; nt < 4; ++nt) {
            short8 w = *(const short8*)&lCAT[SWZ128(nt * 16 + l15, ks * 32 + kb)];
            accB[nt] = MFMA(af, w, accB[nt]);
        }
    }
    float entv[4][4];
    #pragma unroll
    for (int nt = 0; nt < 4; ++nt) {
        #pragma unroll
        for (int reg = 0; reg < 4; ++reg) {
            entv[nt][reg] = accB[nt][reg] + biasEnt[nt];
            E[SWZ64(lg * 4 + reg, nt * 16 + l15)] = bfr(entv[nt][reg]);
        }
    }

    // ---- C: tmp = ent @ WQKT (N=80; col 64 = si); ef reused for D ----
    f32x4 accC[5] = {zero4, zero4, zero4, zero4, zero4};
    short8 ef0 = *(const short8*)&E[SWZ64(l15, 0 * 32 + kb)];
    short8 ef1 = *(const short8*)&E[SWZ64(l15, 1 * 32 + kb)];
    #pragma unroll
    for (int nt = 0; nt < 5; ++nt) {
        short8 w0 = *(const short8*)&lWQKT[SWZ64(nt * 16 + l15, 0 * 32 + kb)];
        short8 w1 = *(const short8*)&lWQKT[SWZ64(nt * 16 + l15, 1 * 32 + kb)];
        accC[nt] = MFMA(ef0, w0, accC[nt]);
        accC[nt] = MFMA(ef1, w1, accC[nt]);
    }
    const int src = lane & 48;
    float si[4];
    #pragma unroll
    for (int reg = 0; reg < 4; ++reg) si[reg] = __shfl(accC[4][reg], src);
    #pragma unroll
    for (int nt = 0; nt < 4; ++nt)
        #pragma unroll
        for (int reg = 0; reg < 4; ++reg)
            T[SWZ64(lg * 4 + reg, nt * 16 + l15)] = bfr(accC[nt][reg]);

    // ---- D: energy = tmp @ ent^T (K=64) + si ----
    f32x4 en = zero4;
    {
        short8 ta0 = *(const short8*)&T[SWZ64(l15, 0 * 32 + kb)];
        short8 ta1 = *(const short8*)&T[SWZ64(l15, 1 * 32 + kb)];
        en = MFMA(ta0, ef0, en);
        en = MFMA(ta1, ef1, en);
    }
    #pragma unroll
    for (int reg = 0; reg < 4; ++reg) en[reg] += si[reg];

    // ---- softmax over i (rows i = lg*4+reg; col j = l15) ----
    float mx = fmaxf(fmaxf(en[0], en[1]), fmaxf(en[2], en[3]));
    mx = fmaxf(mx, __shfl_xor(mx, 16));
    mx = fmaxf(mx, __shfl_xor(mx, 32));
    float p0 = __expf(en[0] - mx), p1 = __expf(en[1] - mx);
    float p2 = __expf(en[2] - mx), p3 = __expf(en[3] - mx);
    float s = p0 + p1 + p2 + p3;
    s += __shfl_xor(s, 16);
    s += __shfl_xor(s, 32);
    float inv = 1.f / s;
    float r0 = p0 * inv, r1 = p1 * inv, r2 = p2 * inv, r3 = p3 * inv;

    // ---- rowsum over j via LDS transpose (replaces 16 shuffles) ----
    float* PW = (float*)T;
    PW[(lg * 4 + 0) * 20 + l15] = r0;
    PW[(lg * 4 + 1) * 20 + l15] = r1;
    PW[(lg * 4 + 2) * 20 + l15] = r2;
    PW[(lg * 4 + 3) * 20 + l15] = r3;
    float4 q0 = *(const float4*)&PW[l15 * 20 + 0];
    float4 q1 = *(const float4*)&PW[l15 * 20 + 4];
    float4 q2 = *(const float4*)&PW[l15 * 20 + 8];
    float4 q3 = *(const float4*)&PW[l15 * 20 + 12];
    float rs_own = ((q0.x + q0.y) + (q0.z + q0.w)) + ((q1.x + q1.y) + (q1.z + q1.w))
                 + ((q2.x + q2.y) + (q2.z + q2.w)) + ((q3.x + q3.y) + (q3.z + q3.w));
    float rr[4];
    #pragma unroll
    for (int reg = 0; reg < 4; ++reg)
        rr[reg] = __shfl(rs_own, (lane & 48) | (lg * 4 + reg));

    // ---- ao from registers: ao[e] = (1/16) sum_n rs[n]*ent[n][e] ----
    float part[4];
    #pragma unroll
    for (int nt = 0; nt < 4; ++nt) {
        float pp = rr[0] * entv[nt][0] + rr[1] * entv[nt][1]
                 + rr[2] * entv[nt][2] + rr[3] * entv[nt][3];
        pp += __shfl_xor(pp, 16);
        pp += __shfl_xor(pp, 32);
        part[nt] = pp;
    }
    float ao = (lg == 0) ? part[0] : (lg == 1) ? part[1]
             : (lg == 2) ? part[2] : part[3];
    aoG[t * 64 + lane] = bfr(ao * 0.0625f);
}

// ---------------------------------------------------------------------------
__device__ __forceinline__ short8 mmfrag(const float* __restrict__ mp) {
    float a0 = 0.f, a1 = 0.f, a2 = 0.f, a3 = 0.f, a4 = 0.f, a5 = 0.f, a6 = 0.f, a7 = 0.f;
    #pragma unroll
    for (int a = 0; a < 8; ++a) {
        float4 u = *(const float4*)(mp + a * 64);
        float4 v = *(const float4*)(mp + a * 64 + 4);
        a0 += u.x; a1 += u.y; a2 += u.z; a3 += u.w;
        a4 += v.x; a5 += v.y; a6 += v.z; a7 += v.w;
    }
    return cvt8v(make_float4(a0 * 0.125f, a1 * 0.125f, a2 * 0.125f, a3 * 0.125f),
                 make_float4(a4 * 0.125f, a5 * 0.125f, a6 * 0.125f, a7 * 0.125f));
}

// Kernel B: hypernet. 512 threads = 8 waves, 8 tokens/wave, grid 512.
// Chunk loop software-pipelined (w1 of chunk c-1 overlaps h1 of chunk c).
__global__ __launch_bounds__(512) void qmix_hyper(
    const float* __restrict__ agent_qs, const float* __restrict__ states,
    const float* __restrict__ mu,
    const float* __restrict__ v_w2, const float* __restrict__ v_b2,
    const float* __restrict__ hw1_b2, const float* __restrict__ hwf_b2,
    const unsigned short* __restrict__ wsb, const float* __restrict__ wsf,
    const unsigned short* __restrict__ aoG,
    float* __restrict__ out)
{
    __shared__ unsigned short sWb[16384];      // 32KB: ZBRT, then H1T|W2T|WFT
    __shared__ unsigned short sMM[8192];       // [64][64] mean-mu bf16
    __shared__ unsigned short sZT[8][1024];    // per-wave: z [16][64]; h1 tile later
    __shared__ float sB1[8][256];
    __shared__ float sWF[8][256];
    __shared__ float sV[8][8];

    const int tid  = threadIdx.x;
    const int lane = tid & 63;
    const int wv   = tid >> 6;
    const int l15  = lane & 15;
    const int lg   = lane >> 4;
    const int kb   = lg * 8;
    const int T0   = blockIdx.x * 64 + wv * 8;
    const int tokB = blockIdx.x * 64;

    const float* BH1 = wsf + 0;
    const float* BHF = wsf + 64;
    const float* BB1 = wsf + 128;
    const float* BV  = wsf + 160;

    const short8 zero8 = {0, 0, 0, 0, 0, 0, 0, 0};
    const f32x4  zero4 = {0.f, 0.f, 0.f, 0.f};

    for (int i = tid * 8; i < 16384; i += 512 * 8)
        *(short8*)(sWb + i) = *(const short8*)(wsb + E_ZBRT + i);

    short8 zA0 = *(const short8*)&aoG[(size_t)(T0 + (l15 & 7)) * 64 + kb];
    short8 zA1 = *(const short8*)&aoG[(size_t)(T0 + (l15 & 7)) * 64 + 32 + kb];

    // block-cooperative mean-mu -> sMM (coalesced)
    {
        int tok = tid >> 3;
        int e8  = (tid & 7) * 8;
        const float* mp = mu + (size_t)(tokB + tok) * 512 + e8;
        float s0 = 0.f, s1 = 0.f, s2 = 0.f, s3 = 0.f,
              s4 = 0.f, s5 = 0.f, s6 = 0.f, s7 = 0.f;
        #pragma unroll
        for (int a = 0; a < 8; ++a) {
            float4 u = *(const float4*)(mp + a * 64);
            float4 v = *(const float4*)(mp + a * 64 + 4);
            s0 += u.x; s1 += u.y; s2 += u.z; s3 += u.w;
            s4 += v.x; s5 += v.y; s6 += v.z; s7 += v.w;
        }
        short8 r;
        r[0] = (short)bfr(s0 * 0.125f); r[1] = (short)bfr(s1 * 0.125f);
        r[2] = (short)bfr(s2 * 0.125f); r[3] = (short)bfr(s3 * 0.125f);
        r[4] = (short)bfr(s4 * 0.125f); r[5] = (short)bfr(s5 * 0.125f);
        r[6] = (short)bfr(s6 * 0.125f); r[7] = (short)bfr(s7 * 0.125f);
        *(short8*)&sMM[SWZ64(tok, e8)] = r;
    }
    for (int i = lane; i < 512; i += 64) sZT[wv][512 + i] = 0;
    __syncthreads();

    // zbr: [8tok x 128] @ ZBRT[128x128] (rows 8-15 idle)
    f32x4 zb[8] = {zero4, zero4, zero4, zero4, zero4, zero4, zero4, zero4};
    const bool arow = (l15 < 8);
    #pragma unroll
    for (int ks = 0; ks < 4; ++ks) {
        short8 af;
        if (ks == 0)      af = arow ? zA0 : zero8;
        else if (ks == 1) af = arow ? zA1 : zero8;
        else {
            short8 m = *(const short8*)&sMM[SWZ64(wv * 8 + (l15 & 7), (ks - 2) * 32 + kb)];
            af = arow ? m : zero8;
        }
        #pragma unroll
        for (int nt = 0; nt < 8; ++nt) {
            short8 w = *(const short8*)&sWb[SWZ128(nt * 16 + l15, ks * 32 + kb)];
            zb[nt] = MFMA(af, w, zb[nt]);
        }
    }
    __syncthreads();

    for (int i = tid * 8; i < 16384; i += 512 * 8)
        *(short8*)(sWb + i) = *(const short8*)(wsb + E_H1T + i);

    if (lg < 2) {
        #pragma unroll
        for (int nt = 0; nt < 4; ++nt) {          // z = relu(...)
            int col = nt * 16 + l15;
            float bz = BHF[col];
            #pragma unroll
            for (int reg = 0; reg < 4; ++reg)
                sZT[wv][SWZ64(lg * 4 + reg, col)] = bfr(fmaxf(zb[nt][reg] + bz, 0.f));
        }
        #pragma unroll
        for (int nt = 4; nt < 6; ++nt) {          // b1
            int m = (nt - 4) * 16 + l15;
            float bb = BB1[m];
            #pragma unroll
            for (int reg = 0; reg < 4; ++reg)
                sB1[wv][(lg * 4 + reg) * 32 + m] = zb[nt][reg] + bb;
        }
    }
    {                                              // rv -> v scalar per token
        float bv0 = BV[l15], bv1 = BV[16 + l15];
        float vw0 = v_w2[l15], vw1 = v_w2[16 + l15];
        #pragma unroll
        for (int reg = 0; reg < 4; ++reg) {
            float vp = fmaxf(zb[6][reg] + bv0, 0.f) * vw0
                     + fmaxf(zb[7][reg] + bv1, 0.f) * vw1;
            vp += __shfl_xor(vp, 1); vp += __shfl_xor(vp, 2);
            vp += __shfl_xor(vp, 4); vp += __shfl_xor(vp, 8);
            if (l15 == 0 && lg < 2) sV[wv][lg * 4 + reg] = vp;
        }
    }
    __syncthreads();
    const unsigned short* lH1T = sWb;
    const unsigned short* lW2T = sWb + 12288;
    const unsigned short* lWFT = sWb + 14336;

    // wf = |relu(z) @ WFT + b2| (rows 8-15 zero)
    {
        f32x4 wfa = zero4, wfb = zero4;
        #pragma unroll
        for (int ks = 0; ks < 2; ++ks) {
            short8 af = *(const short8*)&sZT[wv][SWZ64(l15, ks * 32 + kb)];
            short8 b0 = *(const short8*)&lWFT[SWZ64(l15, ks * 32 + kb)];
            short8 b1 = *(const short8*)&lWFT[SWZ64(16 + l15, ks * 32 + kb)];
            wfa = MFMA(af, b0, wfa);
            wfb = MFMA(af, b1, wfb);
        }
        if (lg < 2) {
            float hb0 = hwf_b2[l15], hb1 = hwf_b2[16 + l15];
            #pragma unroll
            for (int reg = 0; reg < 4; ++reg) {
                int tok = lg * 4 + reg;
                sWF[wv][tok * 32 + l15]      = fabsf(wfa[reg] + hb0);
                sWF[wv][tok * 32 + 16 + l15] = fabsf(wfb[reg] + hb1);
            }
        }
    }

    // ====== h1/w1: 4 chunks of 2 tokens, SOFTWARE-PIPELINED (one tile) =====
    const float vb2 = v_b2[0];
    const float b20 = hw1_b2[l15], b21 = hw1_b2[16 + l15];
    const int agent = l15 & 7;
    const int toff  = l15 >> 3;
    unsigned short* tile = sZT[wv];           // overlay (z dead after wf)

    // epilogue for chunk c given w1 accumulators
    auto EPI = [&](int c, const f32x4& wa, const f32x4& wb) {
        float hp0 = 0.f, hp1 = 0.f;
        #pragma unroll
        for (int reg = 0; reg < 4; ++reg) {
            int row = lg * 4 + reg;
            float qsv = agent_qs[(size_t)(T0 + c * 2 + (row >> 3)) * 8 + (row & 7)];
            hp0 += qsv * fabsf(wa[reg] + b20);
            hp1 += qsv * fabsf(wb[reg] + b21);
        }
        hp0 += __shfl_xor(hp0, 16);
        hp1 += __shfl_xor(hp1, 16);
        int tokL = c * 2 + (lg >> 1);
        float e0 = hp0 + sB1[wv][tokL * 32 + l15];
        float e1 = hp1 + sB1[wv][tokL * 32 + 16 + l15];
        float hid0 = e0 > 0.f ? e0 : (__expf(e0) - 1.f);
        float hid1 = e1 > 0.f ? e1 : (__expf(e1) - 1.f);
        float q = hid0 * sWF[wv][tokL * 32 + l15]
                + hid1 * sWF[wv][tokL * 32 + 16 + l15];
        q += __shfl_xor(q, 1); q += __shfl_xor(q, 2);
        q += __shfl_xor(q, 4); q += __shfl_xor(q, 8);
        if (l15 == 0 && (lg & 1) == 0)
            out[T0 + tokL] = q + sV[wv][tokL] + vb2;
    };
    // h1 MFMAs for one chunk from A-regs; result into h[]
    auto H1C = [&](float4 u0, float4 u1, float4 u2, float4 u3,
                   float4 m0, float4 m1, float4 m2, float4 m3,
                   short8 a0, short8 a1, f32x4* h) {
        short8 f0 = cvt8v(u0, u1), f1 = cvt8v(u2, u3);
        short8 f2 = cvt8v(m0, m1), f3 = cvt8v(m2, m3);
        #pragma unroll
        for (int ks = 0; ks < 6; ++ks) {
            short8 af = (ks == 0) ? f0 : (ks == 1) ? f1 : (ks == 2) ? f2
                      : (ks == 3) ? f3 : (ks == 4) ? a0 : a1;
            #pragma unroll
            for (int nt = 0; nt < 4; ++nt) {
                short8 w = *(const short8*)&lH1T[SWZ192(nt * 16 + l15, ks * 32 + kb)];
                h[nt] = MFMA(af, w, h[nt]);
            }
        }
    };
    auto TILEW = [&](const f32x4* h) {
        #pragma unroll
        for (int nt = 0; nt < 4; ++nt) {
            int col = nt * 16 + l15;
            float bh = BH1[col];
            #pragma unroll
            for (int reg = 0; reg < 4; ++reg)
                tile[SWZ64(lg * 4 + reg, col)] = bfr(fmaxf(h[nt][reg] + bh, 0.f));
        }
    };

    float4 cs0, cs1, cs2, cs3, cm0, cm1, cm2, cm3;
    short8 ca0, ca1;
    {   // load chunk 0
        const size_t tokA = (size_t)(T0 + toff);
        const float* sp = states + tokA * 1024 + agent * 64 + kb;
        const float* mp = mu + tokA * 512 + agent * 64 + kb;
        cs0 = *(const float4*)sp;        cs1 = *(const float4*)(sp + 4);
        cs2 = *(const float4*)(sp + 32); cs3 = *(const float4*)(sp + 36);
        cm0 = *(const float4*)mp;        cm1 = *(const float4*)(mp + 4);
        cm2 = *(const float4*)(mp + 32); cm3 = *(const float4*)(mp + 36);
        ca0 = *(const short8*)&aoG[tokA * 64 + kb];
        ca1 = *(const short8*)&aoG[tokA * 64 + 32 + kb];
    }
    // prologue: h1(0) -> tile
    {
        float4 u0 = cs0, u1 = cs1, u2 = cs2, u3 = cs3;
        float4 m0 = cm0, m1 = cm1, m2 = cm2, m3 = cm3;
        short8 a0 = ca0, a1 = ca1;
        {   // prefetch chunk 1
            const size_t tokA = (size_t)(T0 + 2 + toff);
            const float* sp = states + tokA * 1024 + agent * 64 + kb;
            const float* mp = mu + tokA * 512 + agent * 64 + kb;
            cs0 = *(const float4*)sp;        cs1 = *(const float4*)(sp + 4);
            cs2 = *(const float4*)(sp + 32); cs3 = *(const float4*)(sp + 36);
            cm0 = *(const float4*)mp;        cm1 = *(const float4*)(mp + 4);
            cm2 = *(const float4*)(mp + 32); cm3 = *(const float4*)(mp + 36);
            ca0 = *(const short8*)&aoG[tokA * 64 + kb];
            ca1 = *(const short8*)&aoG[tokA * 64 + 32 + kb];
        }
        f32x4 h[4] = {zero4, zero4, zero4, zero4};
        H1C(u0, u1, u2, u3, m0, m1, m2, m3, a0, a1, h);
        TILEW(h);
    }

    // pipelined iterations: compute h1(mc) while finishing w1(mc-1)
    #pragma unroll
    for (int mc = 1; mc < 4; ++mc) {
        float4 u0 = cs0, u1 = cs1, u2 = cs2, u3 = cs3;
        float4 m0 = cm0, m1 = cm1, m2 = cm2, m3 = cm3;
        short8 a0 = ca0, a1 = ca1;
        if (mc < 3) {   // prefetch chunk mc+1
            const size_t tokA = (size_t)(T0 + (mc + 1) * 2 + toff);
            const float* sp = states + tokA * 1024 + agent * 64 + kb;
            const float* mp = mu + tokA * 512 + agent * 64 + kb;
            cs0 = *(const float4*)sp;        cs1 = *(const float4*)(sp + 4);
            cs2 = *(const float4*)(sp + 32); cs3 = *(const float4*)(sp + 36);
            cm0 = *(const float4*)mp;        cm1 = *(const float4*)(mp + 4);
            cm2 = *(const float4*)(mp + 32); cm3 = *(const float4*)(mp + 36);
            ca0 = *(const short8*)&aoG[tokA * 64 + kb];
            ca1 = *(const short8*)&aoG[tokA * 64 + 32 + kb];
        }
        // w1 A-frags of chunk mc-1 (issue before the h1 burst)
        short8 afw0 = *(const short8*)&tile[SWZ64(l15, 0 * 32 + kb)];
        short8 afw1 = *(const short8*)&tile[SWZ64(l15, 1 * 32 + kb)];
        // h1 for chunk mc (independent of afw reads)
        f32x4 h[4] = {zero4, zero4, zero4, zero4};
        H1C(u0, u1, u2, u3, m0, m1, m2, m3, a0, a1, h);
        // w1 for chunk mc-1
        f32x4 wa = zero4, wb = zero4;
        {
            short8 b00 = *(const short8*)&lW2T[SWZ64(l15, 0 * 32 + kb)];
            short8 b01 = *(const short8*)&lW2T[SWZ64(l15, 1 * 32 + kb)];
            short8 b10 = *(const short8*)&lW2T[SWZ64(16 + l15, 0 * 32 + kb)];
            short8 b11 = *(const short8*)&lW2T[SWZ64(16 + l15, 1 * 32 + kb)];
            wa = MFMA(afw0, b00, wa); wa = MFMA(afw1, b01, wa);
            wb = MFMA(afw0, b10, wb); wb = MFMA(afw1, b11, wb);
        }
        EPI(mc - 1, wa, wb);
        // overwrite tile with h1(mc) -- after afw reads in program order
        TILEW(h);
    }
    // tail: w1 + epilogue for chunk 3
    {
        short8 afw0 = *(const short8*)&tile[SWZ64(l15, 0 * 32 + kb)];
        short8 afw1 = *(const short8*)&tile[SWZ64(l15, 1 * 32 + kb)];
        f32x4 wa = zero4, wb = zero4;
        short8 b00 = *(const short8*)&lW2T[SWZ64(l15, 0 * 32 + kb)];
        short8 b01 = *(const short8*)&lW2T[SWZ64(l15, 1 * 32 + kb)];
        short8 b10 = *(const short8*)&lW2T[SWZ64(16 + l15, 0 * 32 + kb)];
        short8 b11 = *(const short8*)&lW2T[SWZ64(16 + l15, 1 * 32 + kb)];
        wa = MFMA(afw0, b00, wa); wa = MFMA(afw1, b01, wa);
        wb = MFMA(afw0, b10, wb); wb = MFMA(afw1, b11, wb);
        EPI(3, wa, wb);
    }
}

// ---------------------------------------------------------------------------
extern "C" void kernel_launch(void* const* d_in, const int* in_sizes, int n_in,
                              void* d_out, int out_size, void* d_ws, size_t ws_size,
                              hipStream_t stream)
{
    const float* agent_qs = (const float*)d_in[0];
    const float* states   = (const float*)d_in[1];
    const float* mu       = (const float*)d_in[2];
    const float* ally_w   = (const float*)d_in[3];
    const float* ally_b   = (const float*)d_in[4];
    const float* enemy_w  = (const float*)d_in[5];
    const float* enemy_b  = (const float*)d_in[6];
    const float* q_w      = (const float*)d_in[7];
    // d_in[8] = q_b: cancels in softmax over query axis
    const float* k_w      = (const float*)d_in[9];
    const float* k_b      = (const float*)d_in[10];
    const float* hw1_w1   = (const float*)d_in[11];
    const float* hw1_b1   = (const float*)d_in[12];
    const float* hw1_w2   = (const float*)d_in[13];
    const float* hw1_b2   = (const float*)d_in[14];
    const float* hwf_w1   = (const float*)d_in[15];
    const float* hwf_b1   = (const float*)d_in[16];
    const float* hwf_w2   = (const float*)d_in[17];
    const float* hwf_b2   = (const float*)d_in[18];
    const float* hb1_w    = (const float*)d_in[19];
    const float* hb1_b    = (const float*)d_in[20];
    const float* v_w1     = (const float*)d_in[21];
    const float* v_b1     = (const float*)d_in[22];
    const float* v_w2     = (const float*)d_in[23];
    const float* v_b2     = (const float*)d_in[24];
    const float* tre_w    = (const float*)d_in[25];
    const float* tre_b    = (const float*)d_in[26];

    unsigned short* wsb = (unsigned short*)d_ws;
    float* wsf = (float*)((char*)d_ws + (size_t)E_BF16_TOTAL * 2);
    unsigned short* aoG = wsb + E_AO_US;
    float* out = (float*)d_out;

    hipLaunchKernelGGL(qmix_setup, dim3(181), dim3(256), 0, stream,
                       ally_w, enemy_w, q_w, k_w, k_b,
                       hw1_w1, hw1_b1, hw1_w2,
                       hwf_w1, hwf_b1, hwf_w2,
                       hb1_w, hb1_b, v_w1, v_b1, tre_w, tre_b,
                       wsb, wsf);

    hipLaunchKernelGGL(qmix_attn, dim3(TOKS / 8), dim3(512), 0, stream,
                       states, ally_b, enemy_b, wsb, aoG);

    hipLaunchKernelGGL(qmix_hyper, dim3(TOKS / 64), dim3(512), 0, stream,
                       agent_qs, states, mu, v_w2, v_b2, hw1_b2, hwf_b2,
                       wsb, wsf, aoG, out);
}

// Round 17
// 87.198 us; speedup vs baseline: 1.0358x; 1.0358x over previous
//
#include <hip/hip_runtime.h>
#include <math.h>

// ---------------------------------------------------------------------------
// QMixer forward — FINAL (r15 baseline, best of 16 rounds: 87.4us, 5.4x over
// the fp32 round-1 baseline of 475us).
// Structure: setup (weight fusion/transpose/swizzle into d_ws) -> qmix_attn
// (per-token ent->tmp->energy->softmax->ao; 1 token/wave, 8 waves/block,
// register-ao epilogue, LDS-transpose rowsum) -> qmix_hyper (batched MFMA
// hypernet: zbr/wf/h1/w1; 8 tok/wave, 8-wave blocks, coalesced mean-mu,
// hoisted ao frags, double-buffered A prefetch).
// Algebraic fusions: q_b cancels in query-axis softmax; energy = tmp.ent + si
// with Wqk = q_w k_w^T folded offline; tre never materialized (tre_w folded
// into all four hypernet weight slices); attn_out = rank-1 rowsum trick.
// Ceiling: inputs 202MB -> ~38-45us floor; attn at ~73% HBM share
// (memory-bound-ish), hyper latency-structure-bound (16-row matrices);
// fusion disproven (r14: -80MB traffic, +45us lockstep).
// ---------------------------------------------------------------------------

#define TOKS 32768

typedef __attribute__((ext_vector_type(8))) short short8;
typedef __attribute__((ext_vector_type(4))) float f32x4;

#define MFMA(a, b, c) __builtin_amdgcn_mfma_f32_16x16x32_bf16((a), (b), (c), 0, 0, 0)

// ws element offsets (ushort units for bf16 part) -- all regions SWIZZLED
#define E_CAT   0          // [64][128]
#define E_WQKT  8192       // [80][64]  (row 64 = u)
#define E_ZBRT  13312      // [128][128]
#define E_H1T   29696      // [64][192]
#define E_W2T   41984      // [32][64]
#define E_WFT   44032      // [32][64]
#define E_BF16_TOTAL 46080 // floats (192) start at byte 92160
#define E_AO_US 46464      // ao[32768][64] bf16

__device__ __forceinline__ unsigned short bfr(float x) {
    unsigned u = __builtin_bit_cast(unsigned, x);
    u += 0x7fffu + ((u >> 16) & 1u);           // round-to-nearest-even
    return (unsigned short)(u >> 16);
}
__device__ __forceinline__ float bf2f(unsigned short h) {
    unsigned u = ((unsigned)h) << 16;
    return __builtin_bit_cast(float, u);
}
__device__ __forceinline__ short8 cvt8v(float4 a, float4 b) {
    short8 r;
    r[0] = (short)bfr(a.x); r[1] = (short)bfr(a.y);
    r[2] = (short)bfr(a.z); r[3] = (short)bfr(a.w);
    r[4] = (short)bfr(b.x); r[5] = (short)bfr(b.y);
    r[6] = (short)bfr(b.z); r[7] = (short)bfr(b.w);
    return r;
}
#define SWZ64(r, c)  ((((r) * 64)  + (c)) ^ (((r) & 7) << 3))
#define SWZ128(r, c) ((((r) * 128) + (c)) ^ (((r) & 7) << 3))
#define SWZ192(r, c) ((((r) * 192) + (c)) ^ (((r) & 7) << 3))

// ---------------------------------------------------------------------------
__global__ __launch_bounds__(256) void qmix_setup(
    const float* __restrict__ ally_w, const float* __restrict__ enemy_w,
    const float* __restrict__ q_w, const float* __restrict__ k_w,
    const float* __restrict__ k_b,
    const float* __restrict__ hw1_w1, const float* __restrict__ hw1_b1,
    const float* __restrict__ hw1_w2,
    const float* __restrict__ hwf_w1, const float* __restrict__ hwf_b1,
    const float* __restrict__ hwf_w2,
    const float* __restrict__ hb1_w, const float* __restrict__ hb1_b,
    const float* __restrict__ v_w1, const float* __restrict__ v_b1,
    const float* __restrict__ tre_w, const float* __restrict__ tre_b,
    unsigned short* __restrict__ wsb, float* __restrict__ wsf)
{
    int gid = blockIdx.x * 256 + threadIdx.x;
    if (gid < E_BF16_TOTAL) {
        float v = 0.f;
        int base, r, c, K;
        if (gid < E_WQKT) {                         // CAT [64][128]
            base = E_CAT; K = 128;
            int i = gid - base; r = i >> 7; c = i & 127;
            v = (c < 64) ? ally_w[c * 64 + r] : enemy_w[(c - 64) * 64 + r];
        } else if (gid < E_ZBRT) {                  // WQKT [80][64]
            base = E_WQKT; K = 64;
            int i = gid - base; r = i >> 6; c = i & 63;
            if (r < 64) {
                for (int g = 0; g < 64; ++g) v += q_w[c * 64 + g] * k_w[r * 64 + g];
            } else if (r == 64) {
                for (int g = 0; g < 64; ++g) v += q_w[c * 64 + g] * k_b[g];
            }
        } else if (gid < E_H1T) {                   // ZBRT [128][128]
            base = E_ZBRT; K = 128;
            int i = gid - base; r = i >> 7; c = i & 127;
            if (r < 64) {
                if (c < 64) v = hwf_w1[c * 64 + r];
                else for (int g = 0; g < 64; ++g) v += tre_w[(c - 64) * 64 + g] * hwf_w1[(64 + g) * 64 + r];
            } else if (r < 96) {
                int m = r - 64;
                if (c < 64) v = hb1_w[c * 32 + m];
                else for (int g = 0; g < 64; ++g) v += tre_w[(c - 64) * 64 + g] * hb1_w[(64 + g) * 32 + m];
            } else {
                int m = r - 96;
                if (c < 64) v = v_w1[c * 32 + m];
                else for (int g = 0; g < 64; ++g) v += tre_w[(c - 64) * 64 + g] * v_w1[(64 + g) * 32 + m];
            }
        } else if (gid < E_W2T) {                   // H1T [64][192]
            base = E_H1T; K = 192;
            int i = gid - base; r = i / 192; c = i % 192;
            if (c < 64) v = hw1_w1[(64 + c) * 64 + r];
            else if (c < 128) {
                for (int g = 0; g < 64; ++g) v += tre_w[(c - 64) * 64 + g] * hw1_w1[(128 + g) * 64 + r];
            } else v = hw1_w1[(c - 128) * 64 + r];
        } else if (gid < E_WFT) {                   // W2T [32][64]
            base = E_W2T; K = 64;
            int i = gid - base; r = i >> 6; c = i & 63;
            v = hw1_w2[c * 32 + r];
        } else {                                    // WFT [32][64]
            base = E_WFT; K = 64;
            int i = gid - base; r = i >> 6; c = i & 63;
            v = hwf_w2[c * 32 + r];
        }
        wsb[base + ((r * K + c) ^ ((r & 7) << 3))] = bfr(v);
    } else if (gid < E_BF16_TOTAL + 192) {
        int j = gid - E_BF16_TOTAL; float v;
        if (j < 64) {
            v = hw1_b1[j];
            for (int g = 0; g < 64; ++g) v += tre_b[g] * hw1_w1[(128 + g) * 64 + j];
        } else if (j < 128) {
            int e = j - 64; v = hwf_b1[e];
            for (int g = 0; g < 64; ++g) v += tre_b[g] * hwf_w1[(64 + g) * 64 + e];
        } else if (j < 160) {
            int m = j - 128; v = hb1_b[m];
            for (int g = 0; g < 64; ++g) v += tre_b[g] * hb1_w[(64 + g) * 32 + m];
        } else {
            int m = j - 160; v = v_b1[m];
            for (int g = 0; g < 64; ++g) v += tre_b[g] * v_w1[(64 + g) * 32 + m];
        }
        wsf[j] = v;
    }
}

// ---------------------------------------------------------------------------
// Kernel A: attention. 512 threads, ONE token per wave. LDS-transpose rowsum.
__global__ __launch_bounds__(512) void qmix_attn(
    const float* __restrict__ states,
    const float* __restrict__ ally_b, const float* __restrict__ enemy_b,
    const unsigned short* __restrict__ wsb,
    unsigned short* __restrict__ aoG)
{
    __shared__ unsigned short sWa[13312];      // CAT 8192 + WQKT 5120 (26KB)
    __shared__ unsigned short sE[8][1024];
    __shared__ unsigned short sT[8][1024];     // tmp tile; PW overlay after D

    const int lane = threadIdx.x & 63;
    const int wv   = threadIdx.x >> 6;
    const int l15  = lane & 15;
    const int lg   = lane >> 4;
    const int kb   = lg * 8;
    const size_t t = (size_t)blockIdx.x * 8 + wv;

    const short8 zero8 = {0, 0, 0, 0, 0, 0, 0, 0};
    const f32x4  zero4 = {0.f, 0.f, 0.f, 0.f};

    for (int i = threadIdx.x * 8; i < 13312; i += 512 * 8)
        *(short8*)(sWa + i) = *(const short8*)(wsb + E_CAT + i);

    const int roff = (l15 < 8) ? (l15 * 64 + kb) : (512 + (l15 - 8) * 64 + kb);
    const float* p = states + t * 1024 + roff;
    float4 cur0 = *(const float4*)(p);
    float4 cur1 = *(const float4*)(p + 4);
    float4 cur2 = *(const float4*)(p + 32);
    float4 cur3 = *(const float4*)(p + 36);

    float biasEnt[4];
    #pragma unroll
    for (int nt = 0; nt < 4; ++nt) {
        int col = nt * 16 + l15;
        biasEnt[nt] = (lg < 2) ? ally_b[col] : enemy_b[col];
    }
    __syncthreads();
    const unsigned short* lCAT  = sWa;
    const unsigned short* lWQKT = sWa + 8192;

    unsigned short* E = sE[wv];
    unsigned short* T = sT[wv];

    short8 a01 = cvt8v(cur0, cur1);
    short8 a23 = cvt8v(cur2, cur3);
    const bool isally = (l15 < 8);

    // ---- B: ent = [ally;enemy] @ CAT (block-diag K=128) ----
    f32x4 accB[4] = {zero4, zero4, zero4, zero4};
    #pragma unroll
    for (int ks = 0; ks < 4; ++ks) {
        short8 af;
        if (ks == 0)      af = isally ? a01 : zero8;
        else if (ks == 1) af = isally ? a23 : zero8;
        else if (ks == 2) af = isally ? zero8 : a01;
        else              af = isally ? zero8 : a23;
        #pragma unroll
        for (int nt = 0; nt < 4; ++nt) {
            short8 w = *(const short8*)&lCAT[SWZ128(nt * 16 + l15, ks * 32 + kb)];
            accB[nt] = MFMA(af, w, accB[nt]);
        }
    }
    float entv[4][4];
    #pragma unroll
    for (int nt = 0; nt < 4; ++nt) {
        #pragma unroll
        for (int reg = 0; reg < 4; ++reg) {
            entv[nt][reg] = accB[nt][reg] + biasEnt[nt];
            E[SWZ64(lg * 4 + reg, nt * 16 + l15)] = bfr(entv[nt][reg]);
        }
    }

    // ---- C: tmp = ent @ WQKT (N=80; col 64 = si); ef reused for D ----
    f32x4 accC[5] = {zero4, zero4, zero4, zero4, zero4};
    short8 ef0 = *(const short8*)&E[SWZ64(l15, 0 * 32 + kb)];
    short8 ef1 = *(const short8*)&E[SWZ64(l15, 1 * 32 + kb)];
    #pragma unroll
    for (int nt = 0; nt < 5; ++nt) {
        short8 w0 = *(const short8*)&lWQKT[SWZ64(nt * 16 + l15, 0 * 32 + kb)];
        short8 w1 = *(const short8*)&lWQKT[SWZ64(nt * 16 + l15, 1 * 32 + kb)];
        accC[nt] = MFMA(ef0, w0, accC[nt]);
        accC[nt] = MFMA(ef1, w1, accC[nt]);
    }
    const int src = lane & 48;
    float si[4];
    #pragma unroll
    for (int reg = 0; reg < 4; ++reg) si[reg] = __shfl(accC[4][reg], src);
    #pragma unroll
    for (int nt = 0; nt < 4; ++nt)
        #pragma unroll
        for (int reg = 0; reg < 4; ++reg)
            T[SWZ64(lg * 4 + reg, nt * 16 + l15)] = bfr(accC[nt][reg]);

    // ---- D: energy = tmp @ ent^T (K=64) + si ----
    f32x4 en = zero4;
    {
        short8 ta0 = *(const short8*)&T[SWZ64(l15, 0 * 32 + kb)];
        short8 ta1 = *(const short8*)&T[SWZ64(l15, 1 * 32 + kb)];
        en = MFMA(ta0, ef0, en);
        en = MFMA(ta1, ef1, en);
    }
    #pragma unroll
    for (int reg = 0; reg < 4; ++reg) en[reg] += si[reg];

    // ---- softmax over i (rows i = lg*4+reg; col j = l15) ----
    float mx = fmaxf(fmaxf(en[0], en[1]), fmaxf(en[2], en[3]));
    mx = fmaxf(mx, __shfl_xor(mx, 16));
    mx = fmaxf(mx, __shfl_xor(mx, 32));
    float p0 = __expf(en[0] - mx), p1 = __expf(en[1] - mx);
    float p2 = __expf(en[2] - mx), p3 = __expf(en[3] - mx);
    float s = p0 + p1 + p2 + p3;
    s += __shfl_xor(s, 16);
    s += __shfl_xor(s, 32);
    float inv = 1.f / s;
    float r0 = p0 * inv, r1 = p1 * inv, r2 = p2 * inv, r3 = p3 * inv;

    // ---- rowsum over j via LDS transpose (replaces 16 shuffles) ----
    float* PW = (float*)T;
    PW[(lg * 4 + 0) * 20 + l15] = r0;
    PW[(lg * 4 + 1) * 20 + l15] = r1;
    PW[(lg * 4 + 2) * 20 + l15] = r2;
    PW[(lg * 4 + 3) * 20 + l15] = r3;
    float4 q0 = *(const float4*)&PW[l15 * 20 + 0];
    float4 q1 = *(const float4*)&PW[l15 * 20 + 4];
    float4 q2 = *(const float4*)&PW[l15 * 20 + 8];
    float4 q3 = *(const float4*)&PW[l15 * 20 + 12];
    float rs_own = ((q0.x + q0.y) + (q0.z + q0.w)) + ((q1.x + q1.y) + (q1.z + q1.w))
                 + ((q2.x + q2.y) + (q2.z + q2.w)) + ((q3.x + q3.y) + (q3.z + q3.w));
    float rr[4];
    #pragma unroll
    for (int reg = 0; reg < 4; ++reg)
        rr[reg] = __shfl(rs_own, (lane & 48) | (lg * 4 + reg));

    // ---- ao from registers: ao[e] = (1/16) sum_n rs[n]*ent[n][e] ----
    float part[4];
    #pragma unroll
    for (int nt = 0; nt < 4; ++nt) {
        float pp = rr[0] * entv[nt][0] + rr[1] * entv[nt][1]
                 + rr[2] * entv[nt][2] + rr[3] * entv[nt][3];
        pp += __shfl_xor(pp, 16);
        pp += __shfl_xor(pp, 32);
        part[nt] = pp;
    }
    float ao = (lg == 0) ? part[0] : (lg == 1) ? part[1]
             : (lg == 2) ? part[2] : part[3];
    aoG[t * 64 + lane] = bfr(ao * 0.0625f);
}

// ---------------------------------------------------------------------------
__device__ __forceinline__ short8 mmfrag(const float* __restrict__ mp) {
    float a0 = 0.f, a1 = 0.f, a2 = 0.f, a3 = 0.f, a4 = 0.f, a5 = 0.f, a6 = 0.f, a7 = 0.f;
    #pragma unroll
    for (int a = 0; a < 8; ++a) {
        float4 u = *(const float4*)(mp + a * 64);
        float4 v = *(const float4*)(mp + a * 64 + 4);
        a0 += u.x; a1 += u.y; a2 += u.z; a3 += u.w;
        a4 += v.x; a5 += v.y; a6 += v.z; a7 += v.w;
    }
    return cvt8v(make_float4(a0 * 0.125f, a1 * 0.125f, a2 * 0.125f, a3 * 0.125f),
                 make_float4(a4 * 0.125f, a5 * 0.125f, a6 * 0.125f, a7 * 0.125f));
}

// Kernel B: hypernet. 512 threads = 8 waves, 8 tokens/wave, grid 512.
__global__ __launch_bounds__(512) void qmix_hyper(
    const float* __restrict__ agent_qs, const float* __restrict__ states,
    const float* __restrict__ mu,
    const float* __restrict__ v_w2, const float* __restrict__ v_b2,
    const float* __restrict__ hw1_b2, const float* __restrict__ hwf_b2,
    const unsigned short* __restrict__ wsb, const float* __restrict__ wsf,
    const unsigned short* __restrict__ aoG,
    float* __restrict__ out)
{
    __shared__ unsigned short sWb[16384];      // 32KB: ZBRT, then H1T|W2T|WFT
    __shared__ unsigned short sMM[8192];       // [64][64] mean-mu bf16
    __shared__ unsigned short sZT[8][1024];    // per-wave: z [16][64]; h1 tile later
    __shared__ float sB1[8][256];
    __shared__ float sWF[8][256];
    __shared__ float sV[8][8];

    const int tid  = threadIdx.x;
    const int lane = tid & 63;
    const int wv   = tid >> 6;
    const int l15  = lane & 15;
    const int lg   = lane >> 4;
    const int kb   = lg * 8;
    const int T0   = blockIdx.x * 64 + wv * 8;
    const int tokB = blockIdx.x * 64;

    const float* BH1 = wsf + 0;
    const float* BHF = wsf + 64;
    const float* BB1 = wsf + 128;
    const float* BV  = wsf + 160;

    const short8 zero8 = {0, 0, 0, 0, 0, 0, 0, 0};
    const f32x4  zero4 = {0.f, 0.f, 0.f, 0.f};

    for (int i = tid * 8; i < 16384; i += 512 * 8)
        *(short8*)(sWb + i) = *(const short8*)(wsb + E_ZBRT + i);

    short8 zA0 = *(const short8*)&aoG[(size_t)(T0 + (l15 & 7)) * 64 + kb];
    short8 zA1 = *(const short8*)&aoG[(size_t)(T0 + (l15 & 7)) * 64 + 32 + kb];

    // block-cooperative mean-mu -> sMM (coalesced)
    {
        int tok = tid >> 3;
        int e8  = (tid & 7) * 8;
        const float* mp = mu + (size_t)(tokB + tok) * 512 + e8;
        float s0 = 0.f, s1 = 0.f, s2 = 0.f, s3 = 0.f,
              s4 = 0.f, s5 = 0.f, s6 = 0.f, s7 = 0.f;
        #pragma unroll
        for (int a = 0; a < 8; ++a) {
            float4 u = *(const float4*)(mp + a * 64);
            float4 v = *(const float4*)(mp + a * 64 + 4);
            s0 += u.x; s1 += u.y; s2 += u.z; s3 += u.w;
            s4 += v.x; s5 += v.y; s6 += v.z; s7 += v.w;
        }
        short8 r;
        r[0] = (short)bfr(s0 * 0.125f); r[1] = (short)bfr(s1 * 0.125f);
        r[2] = (short)bfr(s2 * 0.125f); r[3] = (short)bfr(s3 * 0.125f);
        r[4] = (short)bfr(s4 * 0.125f); r[5] = (short)bfr(s5 * 0.125f);
        r[6] = (short)bfr(s6 * 0.125f); r[7] = (short)bfr(s7 * 0.125f);
        *(short8*)&sMM[SWZ64(tok, e8)] = r;
    }
    for (int i = lane; i < 512; i += 64) sZT[wv][512 + i] = 0;
    __syncthreads();

    // zbr: [8tok x 128] @ ZBRT[128x128] (rows 8-15 idle)
    f32x4 zb[8] = {zero4, zero4, zero4, zero4, zero4, zero4, zero4, zero4};
    const bool arow = (l15 < 8);
    #pragma unroll
    for (int ks = 0; ks < 4; ++ks) {
        short8 af;
        if (ks == 0)      af = arow ? zA0 : zero8;
        else if (ks == 1) af = arow ? zA1 : zero8;
        else {
            short8 m = *(const short8*)&sMM[SWZ64(wv * 8 + (l15 & 7), (ks - 2) * 32 + kb)];
            af = arow ? m : zero8;
        }
        #pragma unroll
        for (int nt = 0; nt < 8; ++nt) {
            short8 w = *(const short8*)&sWb[SWZ128(nt * 16 + l15, ks * 32 + kb)];
            zb[nt] = MFMA(af, w, zb[nt]);
        }
    }
    __syncthreads();

    for (int i = tid * 8; i < 16384; i += 512 * 8)
        *(short8*)(sWb + i) = *(const short8*)(wsb + E_H1T + i);

    if (lg < 2) {
        #pragma unroll
        for (int nt = 0; nt < 4; ++nt) {          // z = relu(...)
            int col = nt * 16 + l15;
            float bz = BHF[col];
            #pragma unroll
            for (int reg = 0; reg < 4; ++reg)
                sZT[wv][SWZ64(lg * 4 + reg, col)] = bfr(fmaxf(zb[nt][reg] + bz, 0.f));
        }
        #pragma unroll
        for (int nt = 4; nt < 6; ++nt) {          // b1
            int m = (nt - 4) * 16 + l15;
            float bb = BB1[m];
            #pragma unroll
            for (int reg = 0; reg < 4; ++reg)
                sB1[wv][(lg * 4 + reg) * 32 + m] = zb[nt][reg] + bb;
        }
    }
    {                                              // rv -> v scalar per token
        float bv0 = BV[l15], bv1 = BV[16 + l15];
        float vw0 = v_w2[l15], vw1 = v_w2[16 + l15];
        #pragma unroll
        for (int reg = 0; reg < 4; ++reg) {
            float vp = fmaxf(zb[6][reg] + bv0, 0.f) * vw0
                     + fmaxf(zb[7][reg] + bv1, 0.f) * vw1;
            vp += __shfl_xor(vp, 1); vp += __shfl_xor(vp, 2);
            vp += __shfl_xor(vp, 4); vp += __shfl_xor(vp, 8);
            if (l15 == 0 && lg < 2) sV[wv][lg * 4 + reg] = vp;
        }
    }
    __syncthreads();
    const unsigned short* lH1T = sWb;
    const unsigned short* lW2T = sWb + 12288;
    const unsigned short* lWFT = sWb + 14336;

    // wf = |relu(z) @ WFT + b2| (rows 8-15 zero)
    {
        f32x4 wfa = zero4, wfb = zero4;
        #pragma unroll
        for (int ks = 0; ks < 2; ++ks) {
            short8 af = *(const short8*)&sZT[wv][SWZ64(l15, ks * 32 + kb)];
            short8 b0 = *(const short8*)&lWFT[SWZ64(l15, ks * 32 + kb)];
            short8 b1 = *(const short8*)&lWFT[SWZ64(16 + l15, ks * 32 + kb)];
            wfa = MFMA(af, b0, wfa);
            wfb = MFMA(af, b1, wfb);
        }
        if (lg < 2) {
            float hb0 = hwf_b2[l15], hb1 = hwf_b2[16 + l15];
            #pragma unroll
            for (int reg = 0; reg < 4; ++reg) {
                int tok = lg * 4 + reg;
                sWF[wv][tok * 32 + l15]      = fabsf(wfa[reg] + hb0);
                sWF[wv][tok * 32 + 16 + l15] = fabsf(wfb[reg] + hb1);
            }
        }
    }

    // h1/w1: 4 mini-chunks of 2 tokens, double-buffered A prefetch
    const float vb2 = v_b2[0];
    const float b20 = hw1_b2[l15], b21 = hw1_b2[16 + l15];
    const int agent = l15 & 7;
    const int toff  = l15 >> 3;
    unsigned short* tile = sZT[wv];           // overlay (z dead after wf)

    float4 cs0, cs1, cs2, cs3, cm0, cm1, cm2, cm3;
    short8 ca0, ca1;
    {
        const size_t tokA = (size_t)(T0 + toff);
        const float* sp = states + tokA * 1024 + agent * 64 + kb;
        const float* mp = mu + tokA * 512 + agent * 64 + kb;
        cs0 = *(const float4*)sp;        cs1 = *(const float4*)(sp + 4);
        cs2 = *(const float4*)(sp + 32); cs3 = *(const float4*)(sp + 36);
        cm0 = *(const float4*)mp;        cm1 = *(const float4*)(mp + 4);
        cm2 = *(const float4*)(mp + 32); cm3 = *(const float4*)(mp + 36);
        ca0 = *(const short8*)&aoG[tokA * 64 + kb];
        ca1 = *(const short8*)&aoG[tokA * 64 + 32 + kb];
    }

    for (int mc = 0; mc < 4; ++mc) {
        float4 us0 = cs0, us1 = cs1, us2 = cs2, us3 = cs3;
        float4 um0 = cm0, um1 = cm1, um2 = cm2, um3 = cm3;
        short8 ua0 = ca0, ua1 = ca1;
        if (mc < 3) {                          // prefetch next mini-chunk
            const size_t tokA = (size_t)(T0 + (mc + 1) * 2 + toff);
            const float* sp = states + tokA * 1024 + agent * 64 + kb;
            const float* mp = mu + tokA * 512 + agent * 64 + kb;
            cs0 = *(const float4*)sp;        cs1 = *(const float4*)(sp + 4);
            cs2 = *(const float4*)(sp + 32); cs3 = *(const float4*)(sp + 36);
            cm0 = *(const float4*)mp;        cm1 = *(const float4*)(mp + 4);
            cm2 = *(const float4*)(mp + 32); cm3 = *(const float4*)(mp + 36);
            ca0 = *(const short8*)&aoG[tokA * 64 + kb];
            ca1 = *(const short8*)&aoG[tokA * 64 + 32 + kb];
        }
        short8 f0 = cvt8v(us0, us1), f1 = cvt8v(us2, us3);
        short8 f2 = cvt8v(um0, um1), f3 = cvt8v(um2, um3);

        // h1 = relu([ally | mu | ao] @ H1T + BH1), rows = 2 tok x 8 agents
        f32x4 h[4] = {zero4, zero4, zero4, zero4};
        #pragma unroll
        for (int ks = 0; ks < 6; ++ks) {
            short8 af = (ks == 0) ? f0 : (ks == 1) ? f1 : (ks == 2) ? f2
                      : (ks == 3) ? f3 : (ks == 4) ? ua0 : ua1;
            #pragma unroll
            for (int nt = 0; nt < 4; ++nt) {
                short8 w = *(const short8*)&lH1T[SWZ192(nt * 16 + l15, ks * 32 + kb)];
                h[nt] = MFMA(af, w, h[nt]);
            }
        }
        #pragma unroll
        for (int nt = 0; nt < 4; ++nt) {
            int col = nt * 16 + l15;
            float bh = BH1[col];
            #pragma unroll
            for (int reg = 0; reg < 4; ++reg)
                tile[SWZ64(lg * 4 + reg, col)] = bfr(fmaxf(h[nt][reg] + bh, 0.f));
        }

        // w1 = |h1 @ W2T + b2|
        f32x4 wa = zero4, wb = zero4;
        #pragma unroll
        for (int ks = 0; ks < 2; ++ks) {
            short8 af = *(const short8*)&tile[SWZ64(l15, ks * 32 + kb)];
            short8 b0 = *(const short8*)&lW2T[SWZ64(l15, ks * 32 + kb)];
            short8 b1 = *(const short8*)&lW2T[SWZ64(16 + l15, ks * 32 + kb)];
            wa = MFMA(af, b0, wa);
            wb = MFMA(af, b1, wb);
        }

        // hidden = elu(sum_a qs*|w1| + b1); q = sum_m hidden*wf + v
        float hp0 = 0.f, hp1 = 0.f;
        #pragma unroll
        for (int reg = 0; reg < 4; ++reg) {
            int row = lg * 4 + reg;
            float qsv = agent_qs[(size_t)(T0 + mc * 2 + (row >> 3)) * 8 + (row & 7)];
            hp0 += qsv * fabsf(wa[reg] + b20);
            hp1 += qsv * fabsf(wb[reg] + b21);
        }
        hp0 += __shfl_xor(hp0, 16);
        hp1 += __shfl_xor(hp1, 16);
        int tokL = mc * 2 + (lg >> 1);
        float e0 = hp0 + sB1[wv][tokL * 32 + l15];
        float e1 = hp1 + sB1[wv][tokL * 32 + 16 + l15];
        float hid0 = e0 > 0.f ? e0 : (__expf(e0) - 1.f);
        float hid1 = e1 > 0.f ? e1 : (__expf(e1) - 1.f);
        float q = hid0 * sWF[wv][tokL * 32 + l15]
                + hid1 * sWF[wv][tokL * 32 + 16 + l15];
        q += __shfl_xor(q, 1); q += __shfl_xor(q, 2);
        q += __shfl_xor(q, 4); q += __shfl_xor(q, 8);
        if (l15 == 0 && (lg & 1) == 0)
            out[T0 + tokL] = q + sV[wv][tokL] + vb2;
    }
}

// ---------------------------------------------------------------------------
extern "C" void kernel_launch(void* const* d_in, const int* in_sizes, int n_in,
                              void* d_out, int out_size, void* d_ws, size_t ws_size,
                              hipStream_t stream)
{
    const float* agent_qs = (const float*)d_in[0];
    const float* states   = (const float*)d_in[1];
    const float* mu       = (const float*)d_in[2];
    const float* ally_w   = (const float*)d_in[3];
    const float* ally_b   = (const float*)d_in[4];
    const float* enemy_w  = (const float*)d_in[5];
    const float* enemy_b  = (const float*)d_in[6];
    const float* q_w      = (const float*)d_in[7];
    // d_in[8] = q_b: cancels in softmax over query axis
    const float* k_w      = (const float*)d_in[9];
    const float* k_b      = (const float*)d_in[10];
    const float* hw1_w1   = (const float*)d_in[11];
    const float* hw1_b1   = (const float*)d_in[12];
    const float* hw1_w2   = (const float*)d_in[13];
    const float* hw1_b2   = (const float*)d_in[14];
    const float* hwf_w1   = (const float*)d_in[15];
    const float* hwf_b1   = (const float*)d_in[16];
    const float* hwf_w2   = (const float*)d_in[17];
    const float* hwf_b2   = (const float*)d_in[18];
    const float* hb1_w    = (const float*)d_in[19];
    const float* hb1_b    = (const float*)d_in[20];
    const float* v_w1     = (const float*)d_in[21];
    const float* v_b1     = (const float*)d_in[22];
    const float* v_w2     = (const float*)d_in[23];
    const float* v_b2     = (const float*)d_in[24];
    const float* tre_w    = (const float*)d_in[25];
    const float* tre_b    = (const float*)d_in[26];

    unsigned short* wsb = (unsigned short*)d_ws;
    float* wsf = (float*)((char*)d_ws + (size_t)E_BF16_TOTAL * 2);
    unsigned short* aoG = wsb + E_AO_US;
    float* out = (float*)d_out;

    hipLaunchKernelGGL(qmix_setup, dim3(181), dim3(256), 0, stream,
                       ally_w, enemy_w, q_w, k_w, k_b,
                       hw1_w1, hw1_b1, hw1_w2,
                       hwf_w1, hwf_b1, hwf_w2,
                       hb1_w, hb1_b, v_w1, v_b1, tre_w, tre_b,
                       wsb, wsf);

    hipLaunchKernelGGL(qmix_attn, dim3(TOKS / 8), dim3(512), 0, stream,
                       states, ally_b, enemy_b, wsb, aoG);

    hipLaunchKernelGGL(qmix_hyper, dim3(TOKS / 64), dim3(512), 0, stream,
                       agent_qs, states, mu, v_w2, v_b2, hw1_b2, hwf_b2,
                       wsb, wsf, aoG, out);
}